// Round 12
// baseline (81.588 us; speedup 1.0000x reference)
//
#include <hip/hip_runtime.h>
#include <math.h>

#define DD 2048
#define DTC 0.01f
#define NSTEPS 30

typedef float floatx4 __attribute__((ext_vector_type(4)));

__device__ __forceinline__ void lorenz_deriv(float x, float y, float z,
                                             float sigma, float rho, float beta,
                                             float& dx, float& dy, float& dz) {
    dx = sigma * (y - x);
    dy = x * (rho - z) - y;
    dz = x * y - beta * z;
}

__device__ __forceinline__ float fast_tanh(float p) {
    float e = __expf(2.0f * p);
    return 1.0f - __fdividef(2.0f, e + 1.0f);
}

// K_A: state0 = x @ W_in^T + b_in. Barrier-free wave-per-row design:
// 1024 blocks x 256 thr = 4096 waves; wave g owns rows 4g..4g+3, fully
// independent (no LDS, no __syncthreads). W_in (3x2048) hoisted into 96
// VGPRs once per wave; per row 8 packed 1KB loads + butterfly reduce.
__global__ __launch_bounds__(256, 3) void kA_state0(
    const float* __restrict__ x, const float* __restrict__ W_in,
    const float* __restrict__ b_in, float* __restrict__ state0) {
    const int tid = threadIdx.x;
    const int lane = tid & 63;
    const int wv = tid >> 6;
    const int wave_id = blockIdx.x * 4 + wv;
    const int r0 = wave_id * 4;
    const int c = lane * 4;

    const float b0 = b_in[0], b1 = b_in[1], b2 = b_in[2];

    // Hoist W_in slice: w[k][m] = W_in[k][c + m*256], 24 float4 = 96 VGPR.
    floatx4 w[3][8];
#pragma unroll
    for (int k = 0; k < 3; ++k) {
        const float* p = W_in + (size_t)k * DD + c;
#pragma unroll
        for (int m = 0; m < 8; ++m)
            w[k][m] = *reinterpret_cast<const floatx4*>(p + m * 256);
    }

#pragma unroll
    for (int rr = 0; rr < 4; ++rr) {
        const int r = r0 + rr;
        const float* xp = x + (size_t)r * DD + c;
        floatx4 xv[8];
#pragma unroll
        for (int m = 0; m < 8; ++m)
            xv[m] = *reinterpret_cast<const floatx4*>(xp + m * 256);

        floatx4 a0 = {0.f, 0.f, 0.f, 0.f}, a1 = a0, a2 = a0;
#pragma unroll
        for (int m = 0; m < 8; ++m) {
            a0 += xv[m] * w[0][m];
            a1 += xv[m] * w[1][m];
            a2 += xv[m] * w[2][m];
        }
        float s0 = (a0.x + a0.y) + (a0.z + a0.w);
        float s1 = (a1.x + a1.y) + (a1.z + a1.w);
        float s2 = (a2.x + a2.y) + (a2.z + a2.w);
#pragma unroll
        for (int off = 32; off > 0; off >>= 1) {
            s0 += __shfl_xor(s0, off, 64);
            s1 += __shfl_xor(s1, off, 64);
            s2 += __shfl_xor(s2, off, 64);
        }
        if (lane == 0) {
            float* sp = state0 + (size_t)r * 3;
            sp[0] = s0 + b0;
            sp[1] = s1 + b1;
            sp[2] = s2 + b2;
        }
    }
}

// K_B: one thread per row integrates; side job: transpose W_out -> wsT.
__global__ __launch_bounds__(256) void kB_integrate(
    const float* __restrict__ state0, const float* __restrict__ lorenz,
    float* __restrict__ feats,
    const float* __restrict__ W_out, float* __restrict__ wsT) {
    const int tid = threadIdx.x;
    // Transpose side job: 36864 elems over 64 blocks x 768.
#pragma unroll
    for (int i = 0; i < 3; ++i) {
        const int oidx = blockIdx.x * 768 + i * 256 + tid;
        if (oidx < 18 * DD) {
            wsT[oidx] = W_out[(oidx & 2047) * 18 + (oidx >> 11)];
        }
    }

    const int row = blockIdx.x * 256 + tid;
    const float sigma = fmaxf(fabsf(lorenz[0]), 0.1f);
    const float rho   = fmaxf(fabsf(lorenz[1]), 0.1f);
    const float beta  = fmaxf(fabsf(lorenz[2]), 0.1f);

    float sx = state0[(size_t)row * 3 + 0];
    float sy = state0[(size_t)row * 3 + 1];
    float sz = state0[(size_t)row * 3 + 2];
    const float ix = sx, iy = sy, iz = sz;
    float sux = sx, suy = sy, suz = sz;
    float sqx = sx * sx, sqy = sy * sy, sqz = sz * sz;
    float mnx = sx, mny = sy, mnz = sz;
    float mxx = sx, mxy = sy, mxz = sz;
#pragma unroll 1
    for (int t = 0; t < NSTEPS; ++t) {
        float k1x, k1y, k1z, k2x, k2y, k2z, k3x, k3y, k3z, k4x, k4y, k4z;
        float ax, ay, az;
        lorenz_deriv(sx, sy, sz, sigma, rho, beta, k1x, k1y, k1z);
        ax = sx + 0.5f * DTC * k1x; ay = sy + 0.5f * DTC * k1y; az = sz + 0.5f * DTC * k1z;
        lorenz_deriv(ax, ay, az, sigma, rho, beta, k2x, k2y, k2z);
        ax = sx + 0.5f * DTC * k2x; ay = sy + 0.5f * DTC * k2y; az = sz + 0.5f * DTC * k2z;
        lorenz_deriv(ax, ay, az, sigma, rho, beta, k3x, k3y, k3z);
        ax = sx + DTC * k3x; ay = sy + DTC * k3y; az = sz + DTC * k3z;
        lorenz_deriv(ax, ay, az, sigma, rho, beta, k4x, k4y, k4z);
        sx += (DTC / 6.0f) * (k1x + 2.0f * k2x + 2.0f * k3x + k4x);
        sy += (DTC / 6.0f) * (k1y + 2.0f * k2y + 2.0f * k3y + k4y);
        sz += (DTC / 6.0f) * (k1z + 2.0f * k2z + 2.0f * k3z + k4z);
        sux += sx; suy += sy; suz += sz;
        sqx += sx * sx; sqy += sy * sy; sqz += sz * sz;
        mnx = fminf(mnx, sx); mny = fminf(mny, sy); mnz = fminf(mnz, sz);
        mxx = fmaxf(mxx, sx); mxy = fmaxf(mxy, sy); mxz = fmaxf(mxz, sz);
    }
    const float inv31 = 1.0f / 31.0f;
    const float inv30 = 1.0f / 30.0f;
    const float mex = sux * inv31, mey = suy * inv31, mez = suz * inv31;
    const float vax = fmaxf((sqx - sux * mex) * inv30, 0.0f);
    const float vay = fmaxf((sqy - suy * mey) * inv30, 0.0f);
    const float vaz = fmaxf((sqz - suz * mez) * inv30, 0.0f);
    float* f = feats + (size_t)row * 18;
    f[0]  = ix;  f[1]  = iy;  f[2]  = iz;
    f[3]  = sx;  f[4]  = sy;  f[5]  = sz;
    f[6]  = mex; f[7]  = mey; f[8]  = mez;
    f[9]  = sqrtf(vax); f[10] = sqrtf(vay); f[11] = sqrtf(vaz);
    f[12] = mnx; f[13] = mny; f[14] = mnz;
    f[15] = mxx; f[16] = mxy; f[17] = mxz;
}

// K_C: 32 rows x 1024 cols per block (256 threads, 4 cols/thread).
// Coalesced transposed weights; feats tile in LDS; float4 x; NT stores.
__global__ __launch_bounds__(256) void kC_out(
    const float* __restrict__ x, const float* __restrict__ feats,
    const float* __restrict__ wsT, const float* __restrict__ b_out,
    const float* __restrict__ strength, float* __restrict__ out) {
    __shared__ float f_lds[32 * 18];
    const int tid = threadIdx.x;
    const int row0 = blockIdx.x * 32;
    const int c0 = blockIdx.y * 1024 + tid * 4;

    {
        const float* src = feats + (size_t)row0 * 18;
        f_lds[tid] = src[tid];
        f_lds[tid + 256] = src[tid + 256];
        if (tid < 64) f_lds[tid + 512] = src[tid + 512];
    }

    floatx4 wk[18];
#pragma unroll
    for (int k = 0; k < 18; ++k) {
        wk[k] = *reinterpret_cast<const floatx4*>(wsT + (size_t)k * DD + c0);
    }
    const floatx4 bo = *reinterpret_cast<const floatx4*>(b_out + c0);
    const float sabs = fabsf(strength[0]);
    __syncthreads();

#pragma unroll 1
    for (int r = 0; r < 32; r += 2) {
        const int rowA = row0 + r, rowB = row0 + r + 1;
        const float* fA = f_lds + r * 18;
        const float* fB = f_lds + (r + 1) * 18;
        const floatx4 xA = *reinterpret_cast<const floatx4*>(x + (size_t)rowA * DD + c0);
        const floatx4 xB = *reinterpret_cast<const floatx4*>(x + (size_t)rowB * DD + c0);
        floatx4 pA = bo, pB = bo;
#pragma unroll
        for (int k = 0; k < 18; ++k) {
            pA += fA[k] * wk[k];
            pB += fB[k] * wk[k];
        }
        floatx4 oA, oB;
        oA.x = xA.x + fast_tanh(pA.x) * sabs;
        oA.y = xA.y + fast_tanh(pA.y) * sabs;
        oA.z = xA.z + fast_tanh(pA.z) * sabs;
        oA.w = xA.w + fast_tanh(pA.w) * sabs;
        oB.x = xB.x + fast_tanh(pB.x) * sabs;
        oB.y = xB.y + fast_tanh(pB.y) * sabs;
        oB.z = xB.z + fast_tanh(pB.z) * sabs;
        oB.w = xB.w + fast_tanh(pB.w) * sabs;
        __builtin_nontemporal_store(oA, reinterpret_cast<floatx4*>(out + (size_t)rowA * DD + c0));
        __builtin_nontemporal_store(oB, reinterpret_cast<floatx4*>(out + (size_t)rowB * DD + c0));
    }
}

extern "C" void kernel_launch(void* const* d_in, const int* in_sizes, int n_in,
                              void* d_out, int out_size, void* d_ws, size_t ws_size,
                              hipStream_t stream) {
    const float* x        = (const float*)d_in[0];
    const float* lorenz   = (const float*)d_in[1];
    const float* strength = (const float*)d_in[2];
    const float* W_in     = (const float*)d_in[3];
    const float* b_in     = (const float*)d_in[4];
    const float* W_out    = (const float*)d_in[5];
    const float* b_out    = (const float*)d_in[6];
    float* out = (float*)d_out;

    const int N = in_sizes[0] / DD;  // 16384
    float* state0 = (float*)d_ws;            // N*3 floats
    float* feats  = state0 + (size_t)N * 3;  // N*18 floats
    float* wsT    = feats + (size_t)N * 18;  // 18*2048 floats

    kA_state0<<<N / 16, 256, 0, stream>>>(x, W_in, b_in, state0);
    kB_integrate<<<N / 256, 256, 0, stream>>>(state0, lorenz, feats, W_out, wsT);
    dim3 g3(N / 32, DD / 1024);
    kC_out<<<g3, 256, 0, stream>>>(x, feats, wsT, b_out, strength, out);
}